// Round 1
// baseline (46.410 us; speedup 1.0000x reference)
//
#include <hip/hip_runtime.h>
#include <math.h>

#define Bsz 512
#define Nn 8192
#define Hh 5
#define Ss 10

__device__ __forceinline__ float elu1(float v) {
    return v > 0.0f ? v : expm1f(v);
}

// batch_gain[b] = elu( sum_{j=0..min(100,s)} exp(-0.5*(j/30)^2) * own_gain[s-j] ) + 1
__global__ __launch_bounds__(256) void gain_kernel(
    const int* __restrict__ sort_id,
    const float* __restrict__ own_gain,
    float* __restrict__ bg)
{
    int b = blockIdx.x * 256 + threadIdx.x;
    if (b >= Bsz) return;
    int s = sort_id[b];
    float acc = 0.0f;
    int jmax = s < 100 ? s : 100;
    for (int j = 0; j <= jmax; ++j) {
        double t = (double)j * (1.0 / 30.0);
        float w = (float)exp(-0.5 * t * t);   // match numpy f64 exp -> f32 cast
        acc = fmaf(w, own_gain[s - j], acc);
    }
    bg[b] = elu1(acc) + 1.0f;
}

// out[b,n] = (1 + gain_adjust[n]*bg[b]) * (elu(x + hist_dot + elu(state_dot)) + 1)
__global__ __launch_bounds__(256) void main_kernel(
    const float* __restrict__ x,
    const float* __restrict__ history,   // [B,N,H]
    const float* __restrict__ state,     // [B,S]
    const float* __restrict__ hw,        // [N,H]
    const float* __restrict__ hb,        // [N]
    const float* __restrict__ sW,        // [N,S]
    const float* __restrict__ sb,        // [N]
    const float* __restrict__ ga,        // [N]
    const float* __restrict__ bg,        // [B]
    float* __restrict__ out)             // [B,N]
{
    const int bpb = Nn / 1024;                 // 8 blocks per batch row
    int b  = blockIdx.x / bpb;
    int n0 = (blockIdx.x % bpb) * 1024 + threadIdx.x * 4;

    // block-uniform per-batch values (L1/L2 resident)
    float st[Ss];
    #pragma unroll
    for (int i = 0; i < Ss; ++i) st[i] = state[b * Ss + i];
    float bgb = bg[b];

    size_t base = (size_t)b * Nn + n0;

    float4 xv = *reinterpret_cast<const float4*>(x + base);

    // ---- history dot: hist[q] = hb[n0+q] + sum_h history[b,n,h]*hw[n,h]
    float hist[4];
    {
        float4 hbv = *reinterpret_cast<const float4*>(hb + n0);
        hist[0] = hbv.x; hist[1] = hbv.y; hist[2] = hbv.z; hist[3] = hbv.w;
    }
    const float4* h4 = reinterpret_cast<const float4*>(history + base * Hh);          // 20 floats, 16B-aligned
    const float4* w4 = reinterpret_cast<const float4*>(hw + (size_t)n0 * Hh);
    #pragma unroll
    for (int i = 0; i < 5; ++i) {
        float4 hv = h4[i];
        float4 wv = w4[i];
        float hvv[4] = {hv.x, hv.y, hv.z, hv.w};
        float wvv[4] = {wv.x, wv.y, wv.z, wv.w};
        #pragma unroll
        for (int j = 0; j < 4; ++j) {
            int flat = i * 4 + j;             // flat = q*5 + h
            hist[flat / Hh] = fmaf(hvv[j], wvv[j], hist[flat / Hh]);
        }
    }

    // ---- state dot: sm[q] = sb[n0+q] + sum_s state[b,s]*sW[n,s]
    float sm[4];
    {
        float4 sbv = *reinterpret_cast<const float4*>(sb + n0);
        sm[0] = sbv.x; sm[1] = sbv.y; sm[2] = sbv.z; sm[3] = sbv.w;
    }
    const float4* s4 = reinterpret_cast<const float4*>(sW + (size_t)n0 * Ss);         // 40 floats, 16B-aligned
    #pragma unroll
    for (int i = 0; i < 10; ++i) {
        float4 sv = s4[i];
        float svv[4] = {sv.x, sv.y, sv.z, sv.w};
        #pragma unroll
        for (int j = 0; j < 4; ++j) {
            int flat = i * 4 + j;             // flat = q*10 + s
            sm[flat / Ss] = fmaf(svv[j], st[flat % Ss], sm[flat / Ss]);
        }
    }

    float4 gav = *reinterpret_cast<const float4*>(ga + n0);
    float gaa[4] = {gav.x, gav.y, gav.z, gav.w};
    float xa[4]  = {xv.x, xv.y, xv.z, xv.w};

    float res[4];
    #pragma unroll
    for (int q = 0; q < 4; ++q) {
        float v = xa[q] + hist[q] + elu1(sm[q]);
        v = elu1(v) + 1.0f;
        res[q] = fmaf(gaa[q], bgb, 1.0f) * v;
    }
    *reinterpret_cast<float4*>(out + base) =
        make_float4(res[0], res[1], res[2], res[3]);
}

extern "C" void kernel_launch(void* const* d_in, const int* in_sizes, int n_in,
                              void* d_out, int out_size, void* d_ws, size_t ws_size,
                              hipStream_t stream) {
    const float* x        = (const float*)d_in[0];
    const float* history  = (const float*)d_in[1];
    // d_in[2] = gain (unused)
    const float* state    = (const float*)d_in[3];
    const int*   sort_id  = (const int*)d_in[4];
    const float* hw       = (const float*)d_in[5];
    const float* hb       = (const float*)d_in[6];
    const float* sW       = (const float*)d_in[7];
    const float* sb       = (const float*)d_in[8];
    const float* own_gain = (const float*)d_in[9];
    const float* ga       = (const float*)d_in[10];
    float* out = (float*)d_out;
    float* bg  = (float*)d_ws;   // 512 floats of scratch

    gain_kernel<<<2, 256, 0, stream>>>(sort_id, own_gain, bg);

    const int nblocks = (Bsz * Nn) / 1024;   // 4096
    main_kernel<<<nblocks, 256, 0, stream>>>(x, history, state, hw, hb, sW, sb,
                                             ga, bg, out);
}

// Round 2
// 39.350 us; speedup vs baseline: 1.1794x; 1.1794x over previous
//
#include <hip/hip_runtime.h>
#include <math.h>

#define Bsz 512
#define Nn 8192
#define Hh 5
#define Ss 10
#define KB 8            // batches per block
#define TILE 1024       // n per block

__device__ __forceinline__ float elu1(float v) {
    return v > 0.0f ? v : expm1f(v);
}

// batch_gain[b] = elu( sum_{j=0..min(100,s)} exp(-0.5*(j/30)^2) * own_gain[s-j] ) + 1
__global__ __launch_bounds__(256) void gain_kernel(
    const int* __restrict__ sort_id,
    const float* __restrict__ own_gain,
    float* __restrict__ bg)
{
    int b = blockIdx.x * 256 + threadIdx.x;
    if (b >= Bsz) return;
    int s = sort_id[b];
    float acc = 0.0f;
    int jmax = s < 100 ? s : 100;
    for (int j = 0; j <= jmax; ++j) {
        float t = (float)j * (1.0f / 30.0f);
        float w = expf(-0.5f * t * t);
        acc = fmaf(w, own_gain[s - j], acc);
    }
    bg[b] = elu1(acc) + 1.0f;
}

// Each block: one 1024-wide n-tile, loops over KB batches.
// Weights (hw, sW, hb, sb, ga) held in registers across the batch loop.
__global__ __launch_bounds__(256, 2) void main_kernel(
    const float* __restrict__ x,
    const float* __restrict__ history,   // [B,N,H]
    const float* __restrict__ state,     // [B,S]
    const float* __restrict__ hw,        // [N,H]
    const float* __restrict__ hb,        // [N]
    const float* __restrict__ sW,        // [N,S]
    const float* __restrict__ sb,        // [N]
    const float* __restrict__ ga,        // [N]
    const float* __restrict__ bg,        // [B]
    float* __restrict__ out)             // [B,N]
{
    const int tiles = Nn / TILE;                       // 8
    int tile  = blockIdx.x & (tiles - 1);
    int chunk = blockIdx.x / tiles;
    int n0 = tile * TILE + threadIdx.x * 4;
    int b0 = chunk * KB;

    // ---- load per-n weights ONCE (amortized over KB batches) ----
    float wA[20];                                       // hw[n0..n0+3][0..4]
    {
        const float4* p = reinterpret_cast<const float4*>(hw + (size_t)n0 * Hh);
        #pragma unroll
        for (int i = 0; i < 5; ++i) {
            float4 t = p[i];
            wA[i*4+0] = t.x; wA[i*4+1] = t.y; wA[i*4+2] = t.z; wA[i*4+3] = t.w;
        }
    }
    float wS[40];                                       // sW[n0..n0+3][0..9]
    {
        const float4* p = reinterpret_cast<const float4*>(sW + (size_t)n0 * Ss);
        #pragma unroll
        for (int i = 0; i < 10; ++i) {
            float4 t = p[i];
            wS[i*4+0] = t.x; wS[i*4+1] = t.y; wS[i*4+2] = t.z; wS[i*4+3] = t.w;
        }
    }
    float4 hbv = *reinterpret_cast<const float4*>(hb + n0);
    float4 sbv = *reinterpret_cast<const float4*>(sb + n0);
    float4 gav = *reinterpret_cast<const float4*>(ga + n0);
    float hbb[4] = {hbv.x, hbv.y, hbv.z, hbv.w};
    float sbb[4] = {sbv.x, sbv.y, sbv.z, sbv.w};
    float gaa[4] = {gav.x, gav.y, gav.z, gav.w};

    #pragma unroll
    for (int kb = 0; kb < KB; ++kb) {
        int b = b0 + kb;                                // block-uniform -> scalar loads
        float bgb = bg[b];
        float st[Ss];
        #pragma unroll
        for (int i = 0; i < Ss; ++i) st[i] = state[b * Ss + i];

        size_t base = (size_t)b * Nn + n0;
        float4 xv = *reinterpret_cast<const float4*>(x + base);

        // history[b, n0..n0+3, 0..4] : 20 contiguous floats
        float hv[20];
        {
            const float4* p = reinterpret_cast<const float4*>(history + base * Hh);
            #pragma unroll
            for (int i = 0; i < 5; ++i) {
                float4 t = p[i];
                hv[i*4+0] = t.x; hv[i*4+1] = t.y; hv[i*4+2] = t.z; hv[i*4+3] = t.w;
            }
        }

        float hist[4] = {hbb[0], hbb[1], hbb[2], hbb[3]};
        #pragma unroll
        for (int f = 0; f < 20; ++f)                    // flat = q*5 + h
            hist[f / Hh] = fmaf(hv[f], wA[f], hist[f / Hh]);

        float sm[4] = {sbb[0], sbb[1], sbb[2], sbb[3]};
        #pragma unroll
        for (int f = 0; f < 40; ++f)                    // flat = q*10 + s
            sm[f / Ss] = fmaf(st[f % Ss], wS[f], sm[f / Ss]);

        float xa[4] = {xv.x, xv.y, xv.z, xv.w};
        float res[4];
        #pragma unroll
        for (int q = 0; q < 4; ++q) {
            float v = xa[q] + hist[q] + elu1(sm[q]);
            v = elu1(v) + 1.0f;
            res[q] = fmaf(gaa[q], bgb, 1.0f) * v;
        }
        *reinterpret_cast<float4*>(out + base) =
            make_float4(res[0], res[1], res[2], res[3]);
    }
}

extern "C" void kernel_launch(void* const* d_in, const int* in_sizes, int n_in,
                              void* d_out, int out_size, void* d_ws, size_t ws_size,
                              hipStream_t stream) {
    const float* x        = (const float*)d_in[0];
    const float* history  = (const float*)d_in[1];
    // d_in[2] = gain (unused)
    const float* state    = (const float*)d_in[3];
    const int*   sort_id  = (const int*)d_in[4];
    const float* hw       = (const float*)d_in[5];
    const float* hb       = (const float*)d_in[6];
    const float* sW       = (const float*)d_in[7];
    const float* sb       = (const float*)d_in[8];
    const float* own_gain = (const float*)d_in[9];
    const float* ga       = (const float*)d_in[10];
    float* out = (float*)d_out;
    float* bg  = (float*)d_ws;   // 512 floats of scratch

    gain_kernel<<<2, 256, 0, stream>>>(sort_id, own_gain, bg);

    const int nblocks = (Nn / TILE) * (Bsz / KB);   // 8 * 64 = 512
    main_kernel<<<nblocks, 256, 0, stream>>>(x, history, state, hw, hb, sW, sb,
                                             ga, bg, out);
}

// Round 3
// 37.056 us; speedup vs baseline: 1.2524x; 1.0619x over previous
//
#include <hip/hip_runtime.h>
#include <math.h>

#define Bsz 512
#define Nn 8192
#define Hh 5
#define Ss 10
#define KB 4            // batches per block
#define TILE 1024       // n per block

__device__ __forceinline__ float elu1(float v) {
    return v > 0.0f ? v : expm1f(v);
}

// Fused kernel: per block = one 1024-wide n-tile × KB batches.
// Weights (hw, sW, hb, sb, ga) in registers across the batch loop.
// Batch gains computed in-block by threads 0..KB-1 (LDS broadcast).
__global__ __launch_bounds__(256, 4) void main_kernel(
    const float* __restrict__ x,
    const float* __restrict__ history,   // [B,N,H]
    const float* __restrict__ state,     // [B,S]
    const float* __restrict__ hw,        // [N,H]
    const float* __restrict__ hb,        // [N]
    const float* __restrict__ sW,        // [N,S]
    const float* __restrict__ sb,        // [N]
    const float* __restrict__ ga,        // [N]
    const int*   __restrict__ sort_id,   // [B]
    const float* __restrict__ own_gain,  // [T]
    float* __restrict__ out)             // [B,N]
{
    const int tiles = Nn / TILE;                       // 8
    int tile  = blockIdx.x & (tiles - 1);
    int chunk = blockIdx.x / tiles;
    int n0 = tile * TILE + threadIdx.x * 4;
    int b0 = chunk * KB;

    __shared__ float sBG[KB];

    // ---- per-n weights, loaded ONCE (amortized over KB batches) ----
    float wA[20];                                       // hw[n0..n0+3][0..4]
    {
        const float4* p = reinterpret_cast<const float4*>(hw + (size_t)n0 * Hh);
        #pragma unroll
        for (int i = 0; i < 5; ++i) {
            float4 t = p[i];
            wA[i*4+0] = t.x; wA[i*4+1] = t.y; wA[i*4+2] = t.z; wA[i*4+3] = t.w;
        }
    }
    float wS[40];                                       // sW[n0..n0+3][0..9]
    {
        const float4* p = reinterpret_cast<const float4*>(sW + (size_t)n0 * Ss);
        #pragma unroll
        for (int i = 0; i < 10; ++i) {
            float4 t = p[i];
            wS[i*4+0] = t.x; wS[i*4+1] = t.y; wS[i*4+2] = t.z; wS[i*4+3] = t.w;
        }
    }
    float4 hbv = *reinterpret_cast<const float4*>(hb + n0);
    float4 sbv = *reinterpret_cast<const float4*>(sb + n0);
    float4 gav = *reinterpret_cast<const float4*>(ga + n0);
    float hbb[4] = {hbv.x, hbv.y, hbv.z, hbv.w};
    float sbb[4] = {sbv.x, sbv.y, sbv.z, sbv.w};
    float gaa[4] = {gav.x, gav.y, gav.z, gav.w};

    // ---- batch gains (overlaps with the weight loads above) ----
    if (threadIdx.x < KB) {
        int b = b0 + threadIdx.x;
        int s = sort_id[b];
        float acc = 0.0f;
        int jmax = s < 100 ? s : 100;
        for (int j = 0; j <= jmax; ++j) {
            float t = (float)j * (1.0f / 30.0f);
            acc = fmaf(expf(-0.5f * t * t), own_gain[s - j], acc);
        }
        sBG[threadIdx.x] = elu1(acc) + 1.0f;
    }
    __syncthreads();

    #pragma unroll
    for (int kb = 0; kb < KB; ++kb) {
        int b = b0 + kb;                                // block-uniform
        float bgb = sBG[kb];
        float st[Ss];
        #pragma unroll
        for (int i = 0; i < Ss; ++i) st[i] = state[b * Ss + i];

        size_t base = (size_t)b * Nn + n0;
        float4 xv = *reinterpret_cast<const float4*>(x + base);

        // history[b, n0..n0+3, 0..4] : 20 contiguous floats
        float hv[20];
        {
            const float4* p = reinterpret_cast<const float4*>(history + base * Hh);
            #pragma unroll
            for (int i = 0; i < 5; ++i) {
                float4 t = p[i];
                hv[i*4+0] = t.x; hv[i*4+1] = t.y; hv[i*4+2] = t.z; hv[i*4+3] = t.w;
            }
        }

        float hist[4] = {hbb[0], hbb[1], hbb[2], hbb[3]};
        #pragma unroll
        for (int f = 0; f < 20; ++f)                    // flat = q*5 + h
            hist[f / Hh] = fmaf(hv[f], wA[f], hist[f / Hh]);

        float sm[4] = {sbb[0], sbb[1], sbb[2], sbb[3]};
        #pragma unroll
        for (int f = 0; f < 40; ++f)                    // flat = q*10 + s
            sm[f / Ss] = fmaf(st[f % Ss], wS[f], sm[f / Ss]);

        float xa[4] = {xv.x, xv.y, xv.z, xv.w};
        float res[4];
        #pragma unroll
        for (int q = 0; q < 4; ++q) {
            float v = xa[q] + hist[q] + elu1(sm[q]);
            v = elu1(v) + 1.0f;
            res[q] = fmaf(gaa[q], bgb, 1.0f) * v;
        }
        *reinterpret_cast<float4*>(out + base) =
            make_float4(res[0], res[1], res[2], res[3]);
    }
}

extern "C" void kernel_launch(void* const* d_in, const int* in_sizes, int n_in,
                              void* d_out, int out_size, void* d_ws, size_t ws_size,
                              hipStream_t stream) {
    const float* x        = (const float*)d_in[0];
    const float* history  = (const float*)d_in[1];
    // d_in[2] = gain (unused)
    const float* state    = (const float*)d_in[3];
    const int*   sort_id  = (const int*)d_in[4];
    const float* hw       = (const float*)d_in[5];
    const float* hb       = (const float*)d_in[6];
    const float* sW       = (const float*)d_in[7];
    const float* sb       = (const float*)d_in[8];
    const float* own_gain = (const float*)d_in[9];
    const float* ga       = (const float*)d_in[10];
    float* out = (float*)d_out;

    const int nblocks = (Nn / TILE) * (Bsz / KB);   // 8 * 128 = 1024
    main_kernel<<<nblocks, 256, 0, stream>>>(x, history, state, hw, hb, sW, sb,
                                             ga, sort_id, own_gain, out);
}

// Round 4
// 27.839 us; speedup vs baseline: 1.6671x; 1.3311x over previous
//
#include <hip/hip_runtime.h>
#include <math.h>
#include <stdint.h>

#define Bsz 512
#define Nn 8192
#define Hh 5
#define Ss 10
#define KB 4            // batches per block
#define TILE 1024       // n per block
#define NT 256          // threads per block
#define TILES (Nn / TILE)
#define REG (TILE * Hh) // 5120 floats = 20 KB per history buffer

__device__ __forceinline__ float elu1(float v) {
    return v > 0.0f ? v : expm1f(v);
}

// Stage 5120 consecutive floats (20 KB) global -> LDS, dense, no VGPR roundtrip.
// Wave w covers floats [w*1280, (w+1)*1280) in 5 passes of 256 floats.
// LDS dest is wave-uniform base + lane*16B (HW rule); global src is per-lane.
__device__ __forceinline__ void stage_region(const float* __restrict__ g,
                                             float* l, int wave, int lane) {
    #pragma unroll
    for (int p = 0; p < 5; ++p) {
        int off = wave * 1280 + p * 256;
        __builtin_amdgcn_global_load_lds(
            (const __attribute__((address_space(1))) uint32_t*)(g + off + lane * 4),
            (__attribute__((address_space(3))) uint32_t*)(l + off),
            16, 0, 0);
    }
}

__global__ __launch_bounds__(NT, 4) void main_kernel(
    const float* __restrict__ x,         // [B,N]
    const float* __restrict__ history,   // [B,N,H]
    const float* __restrict__ state,     // [B,S]
    const float* __restrict__ hw,        // [N,H]
    const float* __restrict__ hb,        // [N]
    const float* __restrict__ sW,        // [N,S]
    const float* __restrict__ sb,        // [N]
    const float* __restrict__ ga,        // [N]
    const int*   __restrict__ sort_id,   // [B]
    const float* __restrict__ own_gain,  // [T]
    float* __restrict__ out)             // [B,N]
{
    __shared__ __align__(16) float lds[2 * REG];   // 40 KB -> 4 blocks/CU

    const int tid  = threadIdx.x;
    const int lane = tid & 63;
    const int wave = tid >> 6;
    const int tile  = blockIdx.x & (TILES - 1);
    const int chunk = blockIdx.x / TILES;
    const int n0 = tile * TILE;
    const int b0 = chunk * KB;
    const int nq = n0 + tid * 4;

    // ---- batch gains, wave-parallel (each wave computes all KB redundantly) ----
    // lane group g (16 lanes) handles batch b0+g; lane r covers taps j = r+16k.
    float bgv[KB];
    {
        int grp = lane >> 4;
        int r   = lane & 15;
        int s   = sort_id[b0 + grp];
        int jmax = s < 100 ? s : 100;
        float acc = 0.0f;
        #pragma unroll
        for (int k = 0; k < 7; ++k) {
            int j = r + k * 16;
            if (j <= jmax) {
                float t = (float)j * (1.0f / 30.0f);
                acc = fmaf(expf(-0.5f * t * t), own_gain[s - j], acc);
            }
        }
        acc += __shfl_xor(acc, 1);
        acc += __shfl_xor(acc, 2);
        acc += __shfl_xor(acc, 4);
        acc += __shfl_xor(acc, 8);
        #pragma unroll
        for (int g = 0; g < KB; ++g)
            bgv[g] = elu1(__shfl(acc, g * 16)) + 1.0f;
    }

    // ---- dense per-n loads (already coalesced) ----
    float4 hbv = *reinterpret_cast<const float4*>(hb + nq);
    float4 sbv = *reinterpret_cast<const float4*>(sb + nq);
    float4 gav = *reinterpret_cast<const float4*>(ga + nq);

    // ---- hw tile -> LDS (dense) -> registers ----
    stage_region(hw + (size_t)n0 * Hh, lds, wave, lane);
    __syncthreads();
    float wA[20];
    #pragma unroll
    for (int i = 0; i < 5; ++i) {
        float4 t = *reinterpret_cast<float4*>(&lds[tid * 20 + i * 4]);
        wA[i*4+0] = t.x; wA[i*4+1] = t.y; wA[i*4+2] = t.z; wA[i*4+3] = t.w;
    }
    __syncthreads();

    // ---- sW tile (10240 floats) -> LDS (both buffers) -> registers ----
    stage_region(sW + (size_t)n0 * Ss,       lds,       wave, lane);
    stage_region(sW + (size_t)n0 * Ss + REG, lds + REG, wave, lane);
    __syncthreads();
    float wS[40];
    #pragma unroll
    for (int i = 0; i < 10; ++i) {
        float4 t = *reinterpret_cast<float4*>(&lds[tid * 40 + i * 4]);
        wS[i*4+0] = t.x; wS[i*4+1] = t.y; wS[i*4+2] = t.z; wS[i*4+3] = t.w;
    }
    __syncthreads();

    // ---- prologue: stage history[b0] into buffer 0 ----
    stage_region(history + ((size_t)b0 * Nn + n0) * Hh, lds, wave, lane);
    __syncthreads();

    #pragma unroll
    for (int kb = 0; kb < KB; ++kb) {
        const int b = b0 + kb;
        float* buf = lds + (kb & 1) * REG;

        // issue next batch's staging first (flies during compute)
        if (kb + 1 < KB)
            stage_region(history + ((size_t)(b + 1) * Nn + n0) * Hh,
                         lds + ((kb + 1) & 1) * REG, wave, lane);

        // block-uniform scalar loads
        float st[Ss];
        #pragma unroll
        for (int i = 0; i < Ss; ++i) st[i] = state[b * Ss + i];

        float4 xv = *reinterpret_cast<const float4*>(x + (size_t)b * Nn + nq);

        // history dot from LDS: thread t owns floats [t*20, t*20+20)
        float hist[4] = {hbv.x, hbv.y, hbv.z, hbv.w};
        #pragma unroll
        for (int i = 0; i < 5; ++i) {
            float4 h = *reinterpret_cast<float4*>(&buf[tid * 20 + i * 4]);
            float hv4[4] = {h.x, h.y, h.z, h.w};
            #pragma unroll
            for (int j = 0; j < 4; ++j) {
                int f = i * 4 + j;                 // f = q*5 + h
                hist[f / Hh] = fmaf(hv4[j], wA[f], hist[f / Hh]);
            }
        }

        float sm[4] = {sbv.x, sbv.y, sbv.z, sbv.w};
        #pragma unroll
        for (int f = 0; f < 40; ++f)               // f = q*10 + s
            sm[f / Ss] = fmaf(st[f % Ss], wS[f], sm[f / Ss]);

        float xa[4]  = {xv.x, xv.y, xv.z, xv.w};
        float gaa[4] = {gav.x, gav.y, gav.z, gav.w};
        float res[4];
        #pragma unroll
        for (int q = 0; q < 4; ++q) {
            float v = xa[q] + hist[q] + elu1(sm[q]);
            res[q] = fmaf(gaa[q], bgv[kb], 1.0f) * (elu1(v) + 1.0f);
        }
        *reinterpret_cast<float4*>(out + (size_t)b * Nn + nq) =
            make_float4(res[0], res[1], res[2], res[3]);

        __syncthreads();   // drains this iter's staging; protects buffer reuse
    }
}

extern "C" void kernel_launch(void* const* d_in, const int* in_sizes, int n_in,
                              void* d_out, int out_size, void* d_ws, size_t ws_size,
                              hipStream_t stream) {
    const float* x        = (const float*)d_in[0];
    const float* history  = (const float*)d_in[1];
    // d_in[2] = gain (unused)
    const float* state    = (const float*)d_in[3];
    const int*   sort_id  = (const int*)d_in[4];
    const float* hw       = (const float*)d_in[5];
    const float* hb       = (const float*)d_in[6];
    const float* sW       = (const float*)d_in[7];
    const float* sb       = (const float*)d_in[8];
    const float* own_gain = (const float*)d_in[9];
    const float* ga       = (const float*)d_in[10];
    float* out = (float*)d_out;

    const int nblocks = TILES * (Bsz / KB);   // 8 * 128 = 1024 -> 4 blocks/CU
    main_kernel<<<nblocks, NT, 0, stream>>>(x, history, state, hw, hb, sW, sb,
                                            ga, sort_id, own_gain, out);
}

// Round 5
// 27.076 us; speedup vs baseline: 1.7140x; 1.0282x over previous
//
#include <hip/hip_runtime.h>
#include <math.h>
#include <stdint.h>

#define Bsz 512
#define Nn 8192
#define Hh 5
#define Ss 10
#define KB 8            // batches per block
#define TILE 1024       // n per block
#define NT 256          // threads per block
#define TILES (Nn / TILE)

// LDS float layout (60 KB total, all regions WAVE-PRIVATE -> barrier-free):
//   [w*2560, w*2560+2560)   : wave w's region. Prologue: sW staging (2560 floats).
//                             Main loop: history double buffer (2 x 1280 floats).
//   [10240 + w*1280, +1280) : wave w's hw staging region.
#define LDS_FLOATS 15360

__device__ __forceinline__ float elu1(float v) {
    return v > 0.0f ? v : expm1f(v);
}

// One async global->LDS 16B/lane transfer: 64 lanes x 16 B = 1024 B = 256 floats.
// src is per-lane (pass base + lane*4 floats); dst is wave-uniform base.
__device__ __forceinline__ void gload16(const float* src, float* dst) {
    __builtin_amdgcn_global_load_lds(
        (const __attribute__((address_space(1))) uint32_t*)src,
        (__attribute__((address_space(3))) uint32_t*)dst, 16, 0, 0);
}

__global__ __launch_bounds__(NT, 2) void main_kernel(
    const float* __restrict__ x,         // [B,N]
    const float* __restrict__ history,   // [B,N,H]
    const float* __restrict__ state,     // [B,S]
    const float* __restrict__ hw,        // [N,H]
    const float* __restrict__ hb,        // [N]
    const float* __restrict__ sW,        // [N,S]
    const float* __restrict__ sb,        // [N]
    const float* __restrict__ ga,        // [N]
    const int*   __restrict__ sort_id,   // [B]
    const float* __restrict__ own_gain,  // [T]
    float* __restrict__ out)             // [B,N]
{
    __shared__ __align__(16) float lds[LDS_FLOATS];

    const int tid  = threadIdx.x;
    const int lane = tid & 63;
    const int wave = tid >> 6;
    const int tile  = blockIdx.x & (TILES - 1);
    const int chunk = blockIdx.x / TILES;
    const int n0 = tile * TILE;
    const int b0 = chunk * KB;
    const int nq = n0 + tid * 4;

    float* myreg = &lds[wave * 2560];          // sW staging, then hist dbuf
    float* myhw  = &lds[10240 + wave * 1280];  // hw staging

    // ---- per-n biases (dense, coalesced) ----
    float4 hbv = *reinterpret_cast<const float4*>(hb + nq);
    float4 sbv = *reinterpret_cast<const float4*>(sb + nq);
    float4 gav = *reinterpret_cast<const float4*>(ga + nq);

    // ---- batch gains, wave-parallel: 8 lane-groups x 8 lanes, taps j = r+8k ----
    float bgv[KB];
    {
        int grp = lane >> 3;
        int r   = lane & 7;
        int s   = sort_id[b0 + grp];
        int jmax = s < 100 ? s : 100;
        float acc = 0.0f;
        #pragma unroll
        for (int k = 0; k < 13; ++k) {
            int j = r + k * 8;
            if (j <= jmax) {
                float t = (float)j * (1.0f / 30.0f);
                acc = fmaf(expf(-0.5f * t * t), own_gain[s - j], acc);
            }
        }
        acc += __shfl_xor(acc, 1);
        acc += __shfl_xor(acc, 2);
        acc += __shfl_xor(acc, 4);
        #pragma unroll
        for (int g = 0; g < KB; ++g)
            bgv[g] = elu1(__shfl(acc, g * 8)) + 1.0f;
    }

    // ---- stage sW (10 loads) + hw (5 loads) into wave-private regions ----
    {
        const float* srcS = sW + (size_t)n0 * Ss + wave * 2560 + lane * 4;
        #pragma unroll
        for (int p = 0; p < 10; ++p) gload16(srcS + p * 256, myreg + p * 256);
        const float* srcA = hw + (size_t)n0 * Hh + wave * 1280 + lane * 4;
        #pragma unroll
        for (int p = 0; p < 5; ++p)  gload16(srcA + p * 256, myhw + p * 256);
    }
    asm volatile("s_waitcnt vmcnt(0)" ::: "memory");

    // ---- weights LDS -> registers (wave-private, no barrier needed) ----
    float wS[40], wA[20];
    #pragma unroll
    for (int i = 0; i < 10; ++i) {
        float4 t = *reinterpret_cast<float4*>(&myreg[lane * 40 + i * 4]);
        wS[i*4+0] = t.x; wS[i*4+1] = t.y; wS[i*4+2] = t.z; wS[i*4+3] = t.w;
    }
    #pragma unroll
    for (int i = 0; i < 5; ++i) {
        float4 t = *reinterpret_cast<float4*>(&myhw[lane * 20 + i * 4]);
        wA[i*4+0] = t.x; wA[i*4+1] = t.y; wA[i*4+2] = t.z; wA[i*4+3] = t.w;
    }
    asm volatile("" ::: "memory");   // weights consumed before region reuse below

    // ---- prologue prefetch: history[b0] -> buf0, x[b0] -> reg ----
    {
        const float* src = history + ((size_t)b0 * Nn + n0) * Hh + wave * 1280 + lane * 4;
        #pragma unroll
        for (int p = 0; p < 5; ++p) gload16(src + p * 256, myreg + p * 256);
    }
    float4 xv = *reinterpret_cast<const float4*>(x + (size_t)b0 * Nn + nq);

    #pragma unroll
    for (int kb = 0; kb < KB; ++kb) {
        const int b = b0 + kb;

        // own staged data landed (wave-private; no __syncthreads anywhere)
        asm volatile("s_waitcnt vmcnt(0)" ::: "memory");

        // prefetch next batch into the other half of this wave's region
        float4 xnext = xv;
        if (kb + 1 < KB) {
            const float* src = history + ((size_t)(b + 1) * Nn + n0) * Hh
                               + wave * 1280 + lane * 4;
            float* dst = myreg + ((kb + 1) & 1) * 1280;
            #pragma unroll
            for (int p = 0; p < 5; ++p) gload16(src + p * 256, dst + p * 256);
            xnext = *reinterpret_cast<const float4*>(x + (size_t)(b + 1) * Nn + nq);
        }

        // block-uniform state -> scalar loads
        float st[Ss];
        #pragma unroll
        for (int i = 0; i < Ss; ++i) st[i] = state[b * Ss + i];

        // history dot from this wave's current buffer
        const float* buf = myreg + (kb & 1) * 1280 + lane * 20;
        float hist[4] = {hbv.x, hbv.y, hbv.z, hbv.w};
        #pragma unroll
        for (int i = 0; i < 5; ++i) {
            float4 h = *reinterpret_cast<const float4*>(buf + i * 4);
            float hv4[4] = {h.x, h.y, h.z, h.w};
            #pragma unroll
            for (int j = 0; j < 4; ++j) {
                int f = i * 4 + j;                 // f = q*5 + h
                hist[f / Hh] = fmaf(hv4[j], wA[f], hist[f / Hh]);
            }
        }

        float sm[4] = {sbv.x, sbv.y, sbv.z, sbv.w};
        #pragma unroll
        for (int f = 0; f < 40; ++f)               // f = q*10 + s
            sm[f / Ss] = fmaf(st[f % Ss], wS[f], sm[f / Ss]);

        float xa[4]  = {xv.x, xv.y, xv.z, xv.w};
        float gaa[4] = {gav.x, gav.y, gav.z, gav.w};
        float res[4];
        #pragma unroll
        for (int q = 0; q < 4; ++q) {
            float v = xa[q] + hist[q] + elu1(sm[q]);
            res[q] = fmaf(gaa[q], bgv[kb], 1.0f) * (elu1(v) + 1.0f);
        }
        *reinterpret_cast<float4*>(out + (size_t)b * Nn + nq) =
            make_float4(res[0], res[1], res[2], res[3]);

        xv = xnext;
    }
}

extern "C" void kernel_launch(void* const* d_in, const int* in_sizes, int n_in,
                              void* d_out, int out_size, void* d_ws, size_t ws_size,
                              hipStream_t stream) {
    const float* x        = (const float*)d_in[0];
    const float* history  = (const float*)d_in[1];
    // d_in[2] = gain (unused)
    const float* state    = (const float*)d_in[3];
    const int*   sort_id  = (const int*)d_in[4];
    const float* hw       = (const float*)d_in[5];
    const float* hb       = (const float*)d_in[6];
    const float* sW       = (const float*)d_in[7];
    const float* sb       = (const float*)d_in[8];
    const float* own_gain = (const float*)d_in[9];
    const float* ga       = (const float*)d_in[10];
    float* out = (float*)d_out;

    const int nblocks = TILES * (Bsz / KB);   // 8 * 64 = 512 -> 2 blocks/CU exact
    main_kernel<<<nblocks, NT, 0, stream>>>(x, history, state, hw, hb, sW, sb,
                                            ga, sort_id, own_gain, out);
}